// Round 13
// baseline (833.582 us; speedup 1.0000x reference)
//
#include <hip/hip_runtime.h>
#include <hip/hip_bf16.h>
#include <cstdint>
#include <cstddef>

#define BATCH  256
#define HID    1024
#define TSTEPS 128
#define NBLK   256   // 8 mgrp (32 rows) x 32 jblk (32 cols)
#define NTHR   512   // 8 waves = 2 ngrp (3 n-tiles) x 4 kh (K-slice of 256)

typedef __attribute__((ext_vector_type(8))) short bf16x8;
typedef __attribute__((ext_vector_type(4))) float f32x4;

#define MFMA(a, b, c) __builtin_amdgcn_mfma_f32_16x16x32_bf16((a), (b), (c), 0, 0, 0)

// fast gates: native exp2/rcp (error ~1e-6; absmax margin ~5x)
__device__ inline float fsigmoid(float x) {
    return __builtin_amdgcn_rcpf(1.f + __builtin_amdgcn_exp2f(-1.44269504f * x));
}
__device__ inline float ftanh(float x) {
    return 1.f - 2.f * __builtin_amdgcn_rcpf(1.f + __builtin_amdgcn_exp2f(2.88539008f * x));
}

// ---------------------------------------------------------------------------
// prep: pack w_hh (bf16) frag-major (r8-proven layout):
//   frag g = ((jb*6 + n)*32 + c)*64 + l ; wrow = gate*1024+jb*32+ch*16+(l&15);
//   k = c*32 + (l>>4)*8   (gate=n>>1, ch=n&1)
// h0 -> bf16; flag array zeroed.
// ---------------------------------------------------------------------------
__global__ void prep_kernel(const float* __restrict__ vectors,
                            const float* __restrict__ w_hh,
                            __hip_bfloat16* __restrict__ h0,
                            __hip_bfloat16* __restrict__ w2,
                            unsigned* __restrict__ bar)
{
    const long long stride = (long long)gridDim.x * blockDim.x;
    const long long idx = (long long)blockIdx.x * blockDim.x + threadIdx.x;

    const long long NG = 32LL * 6 * 32 * 64;
    for (long long g = idx; g < NG; g += stride) {
        const int l  = (int)(g & 63);
        const int c  = (int)((g >> 6) & 31);
        const int nj = (int)(g >> 11);
        const int n  = nj % 6;
        const int jb = nj / 6;
        const int gate = n >> 1, ch = n & 1;
        const int wrow = gate * HID + jb * 32 + ch * 16 + (l & 15);
        const int k    = c * 32 + (l >> 4) * 8;
        const float* src = w_hh + (size_t)wrow * HID + k;
        alignas(16) __hip_bfloat16 v[8];
        #pragma unroll
        for (int e = 0; e < 8; ++e) v[e] = __float2bfloat16(src[e]);
        *(bf16x8*)(w2 + g * 8) = *(const bf16x8*)v;
    }

    const long long NH = (long long)BATCH * HID;
    for (long long i = idx; i < NH; i += stride)
        h0[i] = __float2bfloat16(vectors[i]);

    for (long long i = idx; i < 1024; i += stride) bar[i] = 0u;
}

// ---------------------------------------------------------------------------
// Persistent GRU, short-chain edition. r8 geometry (256 blk, 512 thr, 1/CU).
// Per step: [per-wave: poll OWN 8 producer flags -> 16 direct A-loads ->
// GEMM from regs] -> barrier -> epilogue (gates + packed u32 h-store direct)
// -> barrier(drain) -> flag. No LDS A-stage, no hstage: 2 barriers/step.
// Wave kh's K-slice [256kh,256kh+256) is produced by jblks 8kh..8kh+7 only ->
// fine-grained flags let K-slices pipeline across producer skew.
// Weights in registers (96 VGPR). y via masked MFMA; jblk==0 writes out.
// ---------------------------------------------------------------------------
__global__ __launch_bounds__(NTHR, 2)
void gru_persistent(const float* __restrict__ vectors,
                    const float* __restrict__ w_ih,
                    const float* __restrict__ b_ih,
                    const float* __restrict__ b_hh,
                    const float* __restrict__ w_ffn,
                    const float* __restrict__ b_ffn,
                    const float* __restrict__ first_input,
                    __hip_bfloat16* __restrict__ h_a,
                    __hip_bfloat16* __restrict__ h_b,
                    const __hip_bfloat16* __restrict__ w2,
                    unsigned* __restrict__ bar,
                    float* __restrict__ out)
{
    __shared__ float ghp[4][3][32][36];   // 55.3 KB K-partials
    __shared__ float ghy[4][32];          // y K-partials (FIXED size vs r8)
    __shared__ __hip_bfloat16 wffn_lds[1024];

    const int blk  = blockIdx.x;
    const int mgrp = blk >> 5, jblk = blk & 31;
    const int m_base = mgrp * 32, j_base = jblk * 32;
    const int tid  = threadIdx.x;
    const int lane = tid & 63, wv = tid >> 6;
    const int ngrp = wv & 1, kh = wv >> 1;
    const int l15  = lane & 15, kg = lane >> 4;

    // epilogue ownership: thread -> (row eb, col-pair ejc0, ejc0+1)
    const int eb = tid >> 4, ejc0 = (tid & 15) * 2;
    float wih_[2][3], bsA[2], bsB[2], bin_[2], bhn_[2], hreg[2];
    #pragma unroll
    for (int e = 0; e < 2; ++e) {
        const int j = j_base + ejc0 + e;
        #pragma unroll
        for (int g = 0; g < 3; ++g) wih_[e][g] = w_ih[g * HID + j];
        bsA[e] = b_ih[j] + b_hh[j];
        bsB[e] = b_ih[HID + j] + b_hh[HID + j];
        bin_[e] = b_ih[2 * HID + j];
        bhn_[e] = b_hh[2 * HID + j];
        hreg[e] = vectors[(size_t)(m_base + eb) * HID + j];
    }
    const float x0  = first_input[0];
    const float bff = b_ffn[0];

    for (int i = tid; i < 1024; i += NTHR)
        wffn_lds[i] = __float2bfloat16(w_ffn[i]);

    // B weights -> registers, permanently (24 frags = 96 VGPRs)
    bf16x8 Breg[3][8];
    {
        const bf16x8* w2f = (const bf16x8*)w2;
        #pragma unroll
        for (int nn = 0; nn < 3; ++nn)
            #pragma unroll
            for (int cc = 0; cc < 8; ++cc)
                Breg[nn][cc] =
                    w2f[((size_t)(jblk * 6 + ngrp * 3 + nn) * 32 + kh * 8 + cc) * 64 + lane];
    }
    __syncthreads();   // wffn_lds ready

    const bf16x8 zb = {0, 0, 0, 0, 0, 0, 0, 0};
    // A-load element offsets: (m_base + mt*16 + l15)*HID + (kh*8+cc)*32 + kg*8
    const size_t abase = (size_t)(m_base + l15) * HID + kh * 256 + kg * 8;

    for (int t = 0; t <= TSTEPS; ++t) {
        // ---- per-wave: poll own 8 producer flags ----
        if (t > 0 && lane < 8) {
            const unsigned* fp = &bar[mgrp * 32 + kh * 8 + lane];
            while (__hip_atomic_load(fp, __ATOMIC_RELAXED,
                                     __HIP_MEMORY_SCOPE_SYSTEM) < (unsigned)t)
                __builtin_amdgcn_s_sleep(1);
        }

        // ---- 16 direct A-loads (2 m-tiles x 8 cc), IC-coherent ----
        const __hip_bfloat16* hsrc = (t & 1) ? h_b : h_a;
        bf16x8 afr[2][8];
        #pragma unroll
        for (int mt = 0; mt < 2; ++mt)
            #pragma unroll
            for (int cc = 0; cc < 8; ++cc) {
                const __hip_bfloat16* ap = hsrc + abase + mt * 16 * HID + cc * 32;
                asm volatile("global_load_dwordx4 %0, %1, off sc0 sc1"
                             : "=v"(afr[mt][cc]) : "v"(ap) : "memory");
            }
        asm volatile("s_waitcnt vmcnt(0)" ::: "memory");
        __builtin_amdgcn_sched_barrier(0);

        if (t < TSTEPS) {
            // ---- GEMM from registers + local y-MFMA ----
            f32x4 acc00 = {0.f,0.f,0.f,0.f}, acc01 = acc00, acc10 = acc00,
                  acc11 = acc00, acc20 = acc00, acc21 = acc00;
            f32x4 accy0 = acc00, accy1 = acc00;
            #pragma unroll
            for (int cc = 0; cc < 8; ++cc) {
                bf16x8 a0 = afr[0][cc];
                bf16x8 a1 = afr[1][cc];
                acc00 = MFMA(a0, Breg[0][cc], acc00);
                acc01 = MFMA(a1, Breg[0][cc], acc01);
                acc10 = MFMA(a0, Breg[1][cc], acc10);
                acc11 = MFMA(a1, Breg[1][cc], acc11);
                acc20 = MFMA(a0, Breg[2][cc], acc20);
                acc21 = MFMA(a1, Breg[2][cc], acc21);
                if (ngrp == 0 && t > 0) {
                    bf16x8 wfv = *(const bf16x8*)(wffn_lds + (kh * 8 + cc) * 32 + kg * 8);
                    bf16x8 wb = (l15 == 0) ? wfv : zb;
                    accy0 = MFMA(a0, wb, accy0);
                    accy1 = MFMA(a1, wb, accy1);
                }
            }
            {
                const int n0 = ngrp * 3;
                #pragma unroll
                for (int r = 0; r < 4; ++r) {
                    const int rw0 = kg * 4 + r, rw1 = 16 + kg * 4 + r;
                    ghp[kh][(n0    ) >> 1][rw0][(((n0    ) & 1) << 4) + l15] = acc00[r];
                    ghp[kh][(n0    ) >> 1][rw1][(((n0    ) & 1) << 4) + l15] = acc01[r];
                    ghp[kh][(n0 + 1) >> 1][rw0][(((n0 + 1) & 1) << 4) + l15] = acc10[r];
                    ghp[kh][(n0 + 1) >> 1][rw1][(((n0 + 1) & 1) << 4) + l15] = acc11[r];
                    ghp[kh][(n0 + 2) >> 1][rw0][(((n0 + 2) & 1) << 4) + l15] = acc20[r];
                    ghp[kh][(n0 + 2) >> 1][rw1][(((n0 + 2) & 1) << 4) + l15] = acc21[r];
                }
                if (ngrp == 0 && t > 0 && l15 == 0) {
                    #pragma unroll
                    for (int r = 0; r < 4; ++r) {
                        ghy[kh][kg * 4 + r]      = accy0[r];
                        ghy[kh][16 + kg * 4 + r] = accy1[r];
                    }
                }
            }
            __syncthreads();   // ghp/ghy ready

            // ---- epilogue: gates + direct packed h-store ----
            __hip_bfloat16* hnxt = (t & 1) ? h_a : h_b;
            {
                const float x = (t == 0) ? x0
                    : (ghy[0][eb] + ghy[1][eb] + ghy[2][eb] + ghy[3][eb] + bff);
                unsigned pack = 0;
                #pragma unroll
                for (int e = 0; e < 2; ++e) {
                    const int jc = ejc0 + e;
                    float ghr = bsA[e], ghz = bsB[e], ghn = bhn_[e];
                    #pragma unroll
                    for (int p = 0; p < 4; ++p) {
                        ghr += ghp[p][0][eb][jc];
                        ghz += ghp[p][1][eb][jc];
                        ghn += ghp[p][2][eb][jc];
                    }
                    const float rg = fsigmoid(fmaf(x, wih_[e][0], ghr));
                    const float zg = fsigmoid(fmaf(x, wih_[e][1], ghz));
                    const float gin = fmaf(x, wih_[e][2], bin_[e]);
                    const float ng = ftanh(fmaf(rg, ghn, gin));
                    const float hnew = (1.f - zg) * ng + zg * hreg[e];
                    hreg[e] = hnew;
                    const unsigned hb =
                        (unsigned)__builtin_bit_cast(unsigned short, __float2bfloat16(hnew));
                    pack |= hb << (16 * e);
                }
                __hip_atomic_store(
                    (unsigned*)(hnxt + (size_t)(m_base + eb) * HID + j_base + ejc0),
                    pack, __ATOMIC_RELAXED, __HIP_MEMORY_SCOPE_SYSTEM);
                if (t > 0 && jblk == 0 && (tid & 15) == 0)
                    out[(size_t)(m_base + eb) * TSTEPS + (t - 1)] = x;
            }
            __syncthreads();   // drains vmcnt: h stores visible before flag
            if (tid == 0)
                __hip_atomic_store(&bar[mgrp * 32 + jblk], (unsigned)(t + 1),
                                   __ATOMIC_RELAXED, __HIP_MEMORY_SCOPE_SYSTEM);
        } else {
            // ---- t == TSTEPS: final y only ----
            if (ngrp == 0) {
                f32x4 accy0 = {0.f,0.f,0.f,0.f}, accy1 = accy0;
                #pragma unroll
                for (int cc = 0; cc < 8; ++cc) {
                    bf16x8 wfv = *(const bf16x8*)(wffn_lds + (kh * 8 + cc) * 32 + kg * 8);
                    bf16x8 wb = (l15 == 0) ? wfv : zb;
                    accy0 = MFMA(afr[0][cc], wb, accy0);
                    accy1 = MFMA(afr[1][cc], wb, accy1);
                }
                if (l15 == 0) {
                    #pragma unroll
                    for (int r = 0; r < 4; ++r) {
                        ghy[kh][kg * 4 + r]      = accy0[r];
                        ghy[kh][16 + kg * 4 + r] = accy1[r];
                    }
                }
            }
            __syncthreads();
            if (jblk == 0 && tid < 32)
                out[(size_t)(m_base + tid) * TSTEPS + (TSTEPS - 1)] =
                    ghy[0][tid] + ghy[1][tid] + ghy[2][tid] + ghy[3][tid] + bff;
        }
    }
}

extern "C" void kernel_launch(void* const* d_in, const int* in_sizes, int n_in,
                              void* d_out, int out_size, void* d_ws, size_t ws_size,
                              hipStream_t stream)
{
    const float* vectors     = (const float*)d_in[0];
    const float* w_ih        = (const float*)d_in[1];
    const float* w_hh        = (const float*)d_in[2];
    const float* b_ih        = (const float*)d_in[3];
    const float* b_hh        = (const float*)d_in[4];
    const float* w_ffn       = (const float*)d_in[5];
    const float* b_ffn       = (const float*)d_in[6];
    const float* first_input = (const float*)d_in[7];
    float* out = (float*)d_out;

    // workspace carve (~7.4 MB)
    char* p = (char*)d_ws;
    __hip_bfloat16* h_a = (__hip_bfloat16*)p;  p += (size_t)BATCH * HID * 2;
    __hip_bfloat16* h_b = (__hip_bfloat16*)p;  p += (size_t)BATCH * HID * 2;
    __hip_bfloat16* w2  = (__hip_bfloat16*)p;  p += 32LL * 6 * 32 * 64 * 8 * 2;
    unsigned* bar = (unsigned*)p;              p += 1024 * 4;   // flags[256]

    prep_kernel<<<1024, 256, 0, stream>>>(vectors, w_hh, h_a, w2, bar);

    void* args[] = {
        (void*)&vectors, (void*)&w_ih, (void*)&b_ih, (void*)&b_hh,
        (void*)&w_ffn, (void*)&b_ffn, (void*)&first_input,
        (void*)&h_a, (void*)&h_b, (void*)&w2, (void*)&bar, (void*)&out
    };
    hipError_t err = hipLaunchCooperativeKernel((const void*)gru_persistent,
                               dim3(NBLK), dim3(NTHR), args, 0, stream);
    (void)err;
}

// Round 14
// 651.381 us; speedup vs baseline: 1.2797x; 1.2797x over previous
//
#include <hip/hip_runtime.h>
#include <hip/hip_bf16.h>
#include <cstdint>
#include <cstddef>

#define BATCH  256
#define HID    1024
#define TSTEPS 128
#define NBLK   256   // 8 mgrp (32 rows) x 32 jblk (32 cols)
#define NTHR   512   // 8 waves = 8 K-slices of 128; each wave: 6 n-tiles x 2 m-tiles

typedef __attribute__((ext_vector_type(8))) short bf16x8;
typedef __attribute__((ext_vector_type(4))) float f32x4;

#define MFMA(a, b, c) __builtin_amdgcn_mfma_f32_16x16x32_bf16((a), (b), (c), 0, 0, 0)

// fast gates: native exp2/rcp (error ~1e-6; absmax margin ~5x, r12/r13-proven)
__device__ inline float fsigmoid(float x) {
    return __builtin_amdgcn_rcpf(1.f + __builtin_amdgcn_exp2f(-1.44269504f * x));
}
__device__ inline float ftanh(float x) {
    return 1.f - 2.f * __builtin_amdgcn_rcpf(1.f + __builtin_amdgcn_exp2f(2.88539008f * x));
}

// ---------------------------------------------------------------------------
// prep: pack w_hh (bf16) frag-major (r8-proven layout):
//   frag g = ((jb*6 + n)*32 + c)*64 + l ; wrow = gate*1024+jb*32+ch*16+(l&15);
//   k = c*32 + (l>>4)*8   (gate=n>>1, ch=n&1)
// h0 -> bf16; flag array zeroed.
// ---------------------------------------------------------------------------
__global__ void prep_kernel(const float* __restrict__ vectors,
                            const float* __restrict__ w_hh,
                            __hip_bfloat16* __restrict__ h0,
                            __hip_bfloat16* __restrict__ w2,
                            unsigned* __restrict__ bar)
{
    const long long stride = (long long)gridDim.x * blockDim.x;
    const long long idx = (long long)blockIdx.x * blockDim.x + threadIdx.x;

    const long long NG = 32LL * 6 * 32 * 64;
    for (long long g = idx; g < NG; g += stride) {
        const int l  = (int)(g & 63);
        const int c  = (int)((g >> 6) & 31);
        const int nj = (int)(g >> 11);
        const int n  = nj % 6;
        const int jb = nj / 6;
        const int gate = n >> 1, ch = n & 1;
        const int wrow = gate * HID + jb * 32 + ch * 16 + (l & 15);
        const int k    = c * 32 + (l >> 4) * 8;
        const float* src = w_hh + (size_t)wrow * HID + k;
        alignas(16) __hip_bfloat16 v[8];
        #pragma unroll
        for (int e = 0; e < 8; ++e) v[e] = __float2bfloat16(src[e]);
        *(bf16x8*)(w2 + g * 8) = *(const bf16x8*)v;
    }

    const long long NH = (long long)BATCH * HID;
    for (long long i = idx; i < NH; i += stride)
        h0[i] = __float2bfloat16(vectors[i]);

    for (long long i = idx; i < 1024; i += stride) bar[i] = 0u;
}

// ---------------------------------------------------------------------------
// Persistent GRU, per-wave K-slice edition. r8 geometry (256 blk, 512 thr).
// Wave kh owns K-slice [128kh, 128kh+128): polls its 4 producers (jblk
// 4kh..4kh+3), loads its A-frags DIRECT to registers (no duplication: 64KB
// per block per step, = r8's staged traffic), computes all 6 n-tiles x 2
// m-tiles (48 MFMAs). Poll/load/GEMM pipelines overlap ACROSS the 8 waves;
// only 2 block barriers per step (ghp-ready, store-drain).
// Weights in registers (24 frags). y via masked MFMA; jblk==0 writes out.
// ---------------------------------------------------------------------------
__global__ __launch_bounds__(NTHR, 2)
void gru_persistent(const float* __restrict__ vectors,
                    const float* __restrict__ w_ih,
                    const float* __restrict__ b_ih,
                    const float* __restrict__ b_hh,
                    const float* __restrict__ w_ffn,
                    const float* __restrict__ b_ffn,
                    const float* __restrict__ first_input,
                    __hip_bfloat16* __restrict__ h_a,
                    __hip_bfloat16* __restrict__ h_b,
                    const __hip_bfloat16* __restrict__ w2,
                    unsigned* __restrict__ bar,
                    float* __restrict__ out)
{
    __shared__ float ghp[8][3][32][36];   // 110.6 KB K-slice partials
    __shared__ float ghy[8][32];          // y K-slice partials
    __shared__ __hip_bfloat16 wffn_lds[1024];

    const int blk  = blockIdx.x;
    const int mgrp = blk >> 5, jblk = blk & 31;
    const int m_base = mgrp * 32, j_base = jblk * 32;
    const int tid  = threadIdx.x;
    const int lane = tid & 63, kh = tid >> 6;       // wave = K-slice
    const int l15  = lane & 15, kg = lane >> 4;

    // epilogue ownership: thread -> (row eb, col-pair ejc0, ejc0+1)
    const int eb = tid >> 4, ejc0 = (tid & 15) * 2;
    float wih_[2][3], bsA[2], bsB[2], bin_[2], bhn_[2], hreg[2];
    #pragma unroll
    for (int e = 0; e < 2; ++e) {
        const int j = j_base + ejc0 + e;
        #pragma unroll
        for (int g = 0; g < 3; ++g) wih_[e][g] = w_ih[g * HID + j];
        bsA[e] = b_ih[j] + b_hh[j];
        bsB[e] = b_ih[HID + j] + b_hh[HID + j];
        bin_[e] = b_ih[2 * HID + j];
        bhn_[e] = b_hh[2 * HID + j];
        hreg[e] = vectors[(size_t)(m_base + eb) * HID + j];
    }
    const float x0  = first_input[0];
    const float bff = b_ffn[0];

    for (int i = tid; i < 1024; i += NTHR)
        wffn_lds[i] = __float2bfloat16(w_ffn[i]);

    // B weights -> registers: 6 n-tiles x 4 cc for this wave's K-slice
    bf16x8 Breg[6][4];
    {
        const bf16x8* w2f = (const bf16x8*)w2;
        #pragma unroll
        for (int n = 0; n < 6; ++n)
            #pragma unroll
            for (int cc = 0; cc < 4; ++cc)
                Breg[n][cc] =
                    w2f[((size_t)(jblk * 6 + n) * 32 + kh * 4 + cc) * 64 + lane];
    }
    __syncthreads();   // wffn_lds ready

    const bf16x8 zb = {0, 0, 0, 0, 0, 0, 0, 0};
    // A element base: row (m_base + l15), k = kh*128 + cc*32 + kg*8
    const size_t abase = (size_t)(m_base + l15) * HID + kh * 128 + kg * 8;

    for (int t = 0; t <= TSTEPS; ++t) {
        // ---- per-wave: poll own 4 producer flags (wave-lockstep reconverge) ----
        if (t > 0 && lane < 4) {
            const unsigned* fp = &bar[mgrp * 32 + kh * 4 + lane];
            while (__hip_atomic_load(fp, __ATOMIC_RELAXED,
                                     __HIP_MEMORY_SCOPE_SYSTEM) < (unsigned)t)
                __builtin_amdgcn_s_sleep(1);
        }

        // ---- 8 direct A-loads (2 m-tiles x 4 cc) for this K-slice ----
        const __hip_bfloat16* hsrc = (t & 1) ? h_b : h_a;
        bf16x8 afr[2][4];
        #pragma unroll
        for (int mt = 0; mt < 2; ++mt)
            #pragma unroll
            for (int cc = 0; cc < 4; ++cc) {
                const __hip_bfloat16* ap = hsrc + abase + mt * 16 * HID + cc * 32;
                asm volatile("global_load_dwordx4 %0, %1, off sc0 sc1"
                             : "=v"(afr[mt][cc]) : "v"(ap) : "memory");
            }
        asm volatile("s_waitcnt vmcnt(0)" ::: "memory");
        __builtin_amdgcn_sched_barrier(0);

        if (t < TSTEPS) {
            // ---- GEMM: 48 MFMAs (6 n x 2 mt x 4 cc) + y-MFMA ----
            f32x4 acc[6][2];
            #pragma unroll
            for (int n = 0; n < 6; ++n)
                #pragma unroll
                for (int mt = 0; mt < 2; ++mt)
                    acc[n][mt] = (f32x4){0.f, 0.f, 0.f, 0.f};
            f32x4 accy0 = {0.f,0.f,0.f,0.f}, accy1 = accy0;
            #pragma unroll
            for (int cc = 0; cc < 4; ++cc) {
                bf16x8 a0 = afr[0][cc];
                bf16x8 a1 = afr[1][cc];
                #pragma unroll
                for (int n = 0; n < 6; ++n) {
                    acc[n][0] = MFMA(a0, Breg[n][cc], acc[n][0]);
                    acc[n][1] = MFMA(a1, Breg[n][cc], acc[n][1]);
                }
                if (t > 0) {
                    bf16x8 wfv = *(const bf16x8*)(wffn_lds + (kh * 4 + cc) * 32 + kg * 8);
                    bf16x8 wb = (l15 == 0) ? wfv : zb;
                    accy0 = MFMA(a0, wb, accy0);
                    accy1 = MFMA(a1, wb, accy1);
                }
            }
            #pragma unroll
            for (int n = 0; n < 6; ++n) {
                const int gate = n >> 1, ch = n & 1;
                #pragma unroll
                for (int r = 0; r < 4; ++r) {
                    ghp[kh][gate][kg * 4 + r][(ch << 4) + l15]      = acc[n][0][r];
                    ghp[kh][gate][16 + kg * 4 + r][(ch << 4) + l15] = acc[n][1][r];
                }
            }
            if (t > 0 && l15 == 0) {
                #pragma unroll
                for (int r = 0; r < 4; ++r) {
                    ghy[kh][kg * 4 + r]      = accy0[r];
                    ghy[kh][16 + kg * 4 + r] = accy1[r];
                }
            }
            __syncthreads();   // ghp/ghy ready

            // ---- epilogue: gates + direct packed h-store ----
            __hip_bfloat16* hnxt = (t & 1) ? h_a : h_b;
            {
                float x = x0;
                if (t > 0) {
                    x = bff;
                    #pragma unroll
                    for (int p = 0; p < 8; ++p) x += ghy[p][eb];
                }
                unsigned pack = 0;
                #pragma unroll
                for (int e = 0; e < 2; ++e) {
                    const int jc = ejc0 + e;
                    float ghr = bsA[e], ghz = bsB[e], ghn = bhn_[e];
                    #pragma unroll
                    for (int p = 0; p < 8; ++p) {
                        ghr += ghp[p][0][eb][jc];
                        ghz += ghp[p][1][eb][jc];
                        ghn += ghp[p][2][eb][jc];
                    }
                    const float rg = fsigmoid(fmaf(x, wih_[e][0], ghr));
                    const float zg = fsigmoid(fmaf(x, wih_[e][1], ghz));
                    const float gin = fmaf(x, wih_[e][2], bin_[e]);
                    const float ng = ftanh(fmaf(rg, ghn, gin));
                    const float hnew = (1.f - zg) * ng + zg * hreg[e];
                    hreg[e] = hnew;
                    const unsigned hb =
                        (unsigned)__builtin_bit_cast(unsigned short, __float2bfloat16(hnew));
                    pack |= hb << (16 * e);
                }
                __hip_atomic_store(
                    (unsigned*)(hnxt + (size_t)(m_base + eb) * HID + j_base + ejc0),
                    pack, __ATOMIC_RELAXED, __HIP_MEMORY_SCOPE_SYSTEM);
                if (t > 0 && jblk == 0 && (tid & 15) == 0)
                    out[(size_t)(m_base + eb) * TSTEPS + (t - 1)] = x;
            }
            __syncthreads();   // drains vmcnt: h stores visible before flag
            if (tid == 0)
                __hip_atomic_store(&bar[mgrp * 32 + jblk], (unsigned)(t + 1),
                                   __ATOMIC_RELAXED, __HIP_MEMORY_SCOPE_SYSTEM);
        } else {
            // ---- t == TSTEPS: final y only ----
            {
                f32x4 accy0 = {0.f,0.f,0.f,0.f}, accy1 = accy0;
                #pragma unroll
                for (int cc = 0; cc < 4; ++cc) {
                    bf16x8 wfv = *(const bf16x8*)(wffn_lds + (kh * 4 + cc) * 32 + kg * 8);
                    bf16x8 wb = (l15 == 0) ? wfv : zb;
                    accy0 = MFMA(afr[0][cc], wb, accy0);
                    accy1 = MFMA(afr[1][cc], wb, accy1);
                }
                if (l15 == 0) {
                    #pragma unroll
                    for (int r = 0; r < 4; ++r) {
                        ghy[kh][kg * 4 + r]      = accy0[r];
                        ghy[kh][16 + kg * 4 + r] = accy1[r];
                    }
                }
            }
            __syncthreads();
            if (jblk == 0 && tid < 32) {
                float x = bff;
                #pragma unroll
                for (int p = 0; p < 8; ++p) x += ghy[p][tid];
                out[(size_t)(m_base + tid) * TSTEPS + (TSTEPS - 1)] = x;
            }
        }
    }
}

extern "C" void kernel_launch(void* const* d_in, const int* in_sizes, int n_in,
                              void* d_out, int out_size, void* d_ws, size_t ws_size,
                              hipStream_t stream)
{
    const float* vectors     = (const float*)d_in[0];
    const float* w_ih        = (const float*)d_in[1];
    const float* w_hh        = (const float*)d_in[2];
    const float* b_ih        = (const float*)d_in[3];
    const float* b_hh        = (const float*)d_in[4];
    const float* w_ffn       = (const float*)d_in[5];
    const float* b_ffn       = (const float*)d_in[6];
    const float* first_input = (const float*)d_in[7];
    float* out = (float*)d_out;

    // workspace carve (~7.4 MB)
    char* p = (char*)d_ws;
    __hip_bfloat16* h_a = (__hip_bfloat16*)p;  p += (size_t)BATCH * HID * 2;
    __hip_bfloat16* h_b = (__hip_bfloat16*)p;  p += (size_t)BATCH * HID * 2;
    __hip_bfloat16* w2  = (__hip_bfloat16*)p;  p += 32LL * 6 * 32 * 64 * 8 * 2;
    unsigned* bar = (unsigned*)p;              p += 1024 * 4;   // flags[256]

    prep_kernel<<<1024, 256, 0, stream>>>(vectors, w_hh, h_a, w2, bar);

    void* args[] = {
        (void*)&vectors, (void*)&w_ih, (void*)&b_ih, (void*)&b_hh,
        (void*)&w_ffn, (void*)&b_ffn, (void*)&first_input,
        (void*)&h_a, (void*)&h_b, (void*)&w2, (void*)&bar, (void*)&out
    };
    hipError_t err = hipLaunchCooperativeKernel((const void*)gru_persistent,
                               dim3(NBLK), dim3(NTHR), args, 0, stream);
    (void)err;
}

// Round 16
// 570.547 us; speedup vs baseline: 1.4610x; 1.1417x over previous
//
#include <hip/hip_runtime.h>
#include <hip/hip_bf16.h>
#include <cstdint>
#include <cstddef>

#define BATCH  256
#define HID    1024
#define TSTEPS 128
#define NBLK   256   // 8 mgrp (32 rows) x 32 jblk (32 cols) -- 1 block/CU, always launchable
#define NTHR   512   // 8 waves: GEMM role = 2 ngrp x 4 kh; stage role = 8 k16-slices

typedef __attribute__((ext_vector_type(8))) short bf16x8;
typedef __attribute__((ext_vector_type(4))) float f32x4;

#define MFMA(a, b, c) __builtin_amdgcn_mfma_f32_16x16x32_bf16((a), (b), (c), 0, 0, 0)

// fast gates: native exp2/rcp (error ~1e-6; r12-proven, absmax unchanged)
__device__ inline float fsigmoid(float x) {
    return __builtin_amdgcn_rcpf(1.f + __builtin_amdgcn_exp2f(-1.44269504f * x));
}
__device__ inline float ftanh(float x) {
    return 1.f - 2.f * __builtin_amdgcn_rcpf(1.f + __builtin_amdgcn_exp2f(2.88539008f * x));
}

// ---------------------------------------------------------------------------
// prep: pack w_hh (bf16) frag-major (r8-proven layout):
//   frag g = ((jb*6 + n)*32 + c)*64 + l ; wrow = gate*1024+jb*32+ch*16+(l&15);
//   k = c*32 + (l>>4)*8   (gate=n>>1, ch=n&1)
// h0 -> bf16; flag array zeroed.
// ---------------------------------------------------------------------------
__global__ void prep_kernel(const float* __restrict__ vectors,
                            const float* __restrict__ w_hh,
                            __hip_bfloat16* __restrict__ h0,
                            __hip_bfloat16* __restrict__ w2,
                            unsigned* __restrict__ bar)
{
    const long long stride = (long long)gridDim.x * blockDim.x;
    const long long idx = (long long)blockIdx.x * blockDim.x + threadIdx.x;

    const long long NG = 32LL * 6 * 32 * 64;
    for (long long g = idx; g < NG; g += stride) {
        const int l  = (int)(g & 63);
        const int c  = (int)((g >> 6) & 31);
        const int nj = (int)(g >> 11);
        const int n  = nj % 6;
        const int jb = nj / 6;
        const int gate = n >> 1, ch = n & 1;
        const int wrow = gate * HID + jb * 32 + ch * 16 + (l & 15);
        const int k    = c * 32 + (l >> 4) * 8;
        const float* src = w_hh + (size_t)wrow * HID + k;
        alignas(16) __hip_bfloat16 v[8];
        #pragma unroll
        for (int e = 0; e < 8; ++e) v[e] = __float2bfloat16(src[e]);
        *(bf16x8*)(w2 + g * 8) = *(const bf16x8*)v;
    }

    const long long NH = (long long)BATCH * HID;
    for (long long i = idx; i < NH; i += stride)
        h0[i] = __float2bfloat16(vectors[i]);

    for (long long i = idx; i < 1024; i += stride) bar[i] = 0u;
}

// ---------------------------------------------------------------------------
// Persistent GRU, consolidated. r8 geometry (256 blk x 512 thr, 1 block/CU --
// launch validity is unconditional; r10/r11/r15 all died on occupancy bets).
// Deltas vs r8 (each proven in a passing round):
//  1. Per-wave staging: wave w stages A k16-slice [16w,16w+16) and polls only
//     its 4 producers (jblk 4w..4w+3) -> producer skew pipelines across waves.
//  2. No hstage: epilogue stores h directly (packed u32, system scope).
//  3. Fast gates + folded r/z biases.
// Weights in registers (24 frags). y via masked MFMA; jblk==0 writes out.
// 4 syncs/step. Protocol (drain-then-flag, relaxed system atomics) = r8.
// ---------------------------------------------------------------------------
__global__ __launch_bounds__(NTHR, 2)
void gru_persistent(const float* __restrict__ vectors,
                    const float* __restrict__ w_ih,
                    const float* __restrict__ b_ih,
                    const float* __restrict__ b_hh,
                    const float* __restrict__ w_ffn,
                    const float* __restrict__ b_ffn,
                    const float* __restrict__ first_input,
                    __hip_bfloat16* __restrict__ h_a,
                    __hip_bfloat16* __restrict__ h_b,
                    const __hip_bfloat16* __restrict__ w2,
                    unsigned* __restrict__ bar,
                    float* __restrict__ out)
{
    __shared__ alignas(16) unsigned char ldsA[65536];   // h_t staged, swizzled
    __shared__ float ghp[4][3][32][36];                 // gh K-partials
    __shared__ float ghy[4][32];                        // y K-partials
    __shared__ __hip_bfloat16 wffn_lds[1024];

    const int blk  = blockIdx.x;
    const int xcd  = blk & 7, q = blk >> 3;
    const int jblk = xcd * 4 + (q & 3);
    const int mgrp = q >> 2;
    const int m_base = mgrp * 32, j_base = jblk * 32;
    const int tid  = threadIdx.x;
    const int lane = tid & 63, wv = tid >> 6;
    const int ngrp = wv & 1, kh = wv >> 1;
    const int l15  = lane & 15, kg = lane >> 4;

    // epilogue ownership: thread -> (row eb, col-pair ejc0, ejc0+1) of 32x32
    const int eb = tid >> 4, ejc0 = (tid & 15) * 2;
    float wih_[2][3], bsA[2], bsB[2], bin_[2], bhn_[2], hreg[2];
    #pragma unroll
    for (int e = 0; e < 2; ++e) {
        const int j = j_base + ejc0 + e;
        #pragma unroll
        for (int g = 0; g < 3; ++g) wih_[e][g] = w_ih[g * HID + j];
        bsA[e] = b_ih[j] + b_hh[j];
        bsB[e] = b_ih[HID + j] + b_hh[HID + j];
        bin_[e] = b_ih[2 * HID + j];
        bhn_[e] = b_hh[2 * HID + j];
        hreg[e] = vectors[(size_t)(m_base + eb) * HID + j];
    }
    const float x0  = first_input[0];
    const float bff = b_ffn[0];

    for (int i = tid; i < 1024; i += NTHR)
        wffn_lds[i] = __float2bfloat16(w_ffn[i]);

    // B weights -> registers, permanently (24 frags = 96 VGPRs)
    bf16x8 Breg[3][8];
    {
        const bf16x8* w2f = (const bf16x8*)w2;
        #pragma unroll
        for (int nn = 0; nn < 3; ++nn)
            #pragma unroll
            for (int cc = 0; cc < 8; ++cc)
                Breg[nn][cc] =
                    w2f[((size_t)(jblk * 6 + ngrp * 3 + nn) * 32 + kh * 8 + cc) * 64 + lane];
    }
    __syncthreads();   // wffn_lds ready

    const int swz = (l15 & 7) << 4;
    const int rb0 = l15 * 2048, rb1 = (16 + l15) * 2048;
    const bf16x8 zb = {0, 0, 0, 0, 0, 0, 0, 0};

    for (int t = 0; t <= TSTEPS; ++t) {
        // ---- per-wave: poll own 4 producers, then stage own k16-slice ----
        if (t > 0 && lane < 4) {
            const unsigned* fp = &bar[mgrp * 32 + wv * 4 + lane];
            while (__hip_atomic_load(fp, __ATOMIC_RELAXED,
                                     __HIP_MEMORY_SCOPE_SYSTEM) < (unsigned)t)
                __builtin_amdgcn_s_sleep(1);
        }
        const __hip_bfloat16* hcur = (t & 1) ? h_b : h_a;
        __hip_bfloat16* hnxt = (t & 1) ? h_a : h_b;
        {
            const uint4* srcA = (const uint4*)(hcur + (size_t)m_base * HID);
            uint4 tmp[8];
            #pragma unroll
            for (int it = 0; it < 8; ++it) {
                const int c = lane + it * 64;           // 0..511 within wave
                const int row = c >> 4;
                const int k16 = (wv << 4) + (c & 15);   // wave's slice
                asm volatile("global_load_dwordx4 %0, %1, off sc0 sc1"
                             : "=v"(tmp[it]) : "v"(srcA + row * 128 + k16) : "memory");
            }
            asm volatile("s_waitcnt vmcnt(0)" ::: "memory");
            #pragma unroll
            for (int it = 0; it < 8; ++it) {
                const int c = lane + it * 64;
                const int row = c >> 4;
                const int k16 = (wv << 4) + (c & 15);
                const int bo = row * 2048 + ((k16 << 4) ^ ((row & 7) << 4));
                *(uint4*)(ldsA + bo) = tmp[it];
            }
        }
        __syncthreads();   // full A tile ready

        if (t < TSTEPS) {
            // ---- GEMM (B from regs) + local y-MFMA ----
            f32x4 acc00 = {0.f,0.f,0.f,0.f}, acc01 = acc00, acc10 = acc00,
                  acc11 = acc00, acc20 = acc00, acc21 = acc00;
            f32x4 accy0 = acc00, accy1 = acc00;
            #pragma unroll
            for (int cc = 0; cc < 8; ++cc) {
                const int c = (kh << 3) + cc;
                const int colb = ((c << 6) | (kg << 4)) ^ swz;
                bf16x8 a0 = *(const bf16x8*)(ldsA + rb0 + colb);
                bf16x8 a1 = *(const bf16x8*)(ldsA + rb1 + colb);
                acc00 = MFMA(a0, Breg[0][cc], acc00);
                acc01 = MFMA(a1, Breg[0][cc], acc01);
                acc10 = MFMA(a0, Breg[1][cc], acc10);
                acc11 = MFMA(a1, Breg[1][cc], acc11);
                acc20 = MFMA(a0, Breg[2][cc], acc20);
                acc21 = MFMA(a1, Breg[2][cc], acc21);
                if (ngrp == 0 && t > 0) {
                    bf16x8 wfv = *(const bf16x8*)(wffn_lds + c * 32 + kg * 8);
                    bf16x8 wb = (l15 == 0) ? wfv : zb;
                    accy0 = MFMA(a0, wb, accy0);
                    accy1 = MFMA(a1, wb, accy1);
                }
            }
            {
                const int n0 = ngrp * 3;
                #pragma unroll
                for (int r = 0; r < 4; ++r) {
                    const int rw0 = kg * 4 + r, rw1 = 16 + kg * 4 + r;
                    ghp[kh][(n0    ) >> 1][rw0][(((n0    ) & 1) << 4) + l15] = acc00[r];
                    ghp[kh][(n0    ) >> 1][rw1][(((n0    ) & 1) << 4) + l15] = acc01[r];
                    ghp[kh][(n0 + 1) >> 1][rw0][(((n0 + 1) & 1) << 4) + l15] = acc10[r];
                    ghp[kh][(n0 + 1) >> 1][rw1][(((n0 + 1) & 1) << 4) + l15] = acc11[r];
                    ghp[kh][(n0 + 2) >> 1][rw0][(((n0 + 2) & 1) << 4) + l15] = acc20[r];
                    ghp[kh][(n0 + 2) >> 1][rw1][(((n0 + 2) & 1) << 4) + l15] = acc21[r];
                }
                if (ngrp == 0 && t > 0 && l15 == 0) {
                    #pragma unroll
                    for (int r = 0; r < 4; ++r) {
                        ghy[kh][kg * 4 + r]      = accy0[r];
                        ghy[kh][16 + kg * 4 + r] = accy1[r];
                    }
                }
            }
            __syncthreads();   // ghp/ghy ready

            // ---- epilogue: fast gates + direct packed h-store ----
            {
                const float x = (t == 0) ? x0
                    : (ghy[0][eb] + ghy[1][eb] + ghy[2][eb] + ghy[3][eb] + bff);
                unsigned pack = 0;
                #pragma unroll
                for (int e = 0; e < 2; ++e) {
                    const int jc = ejc0 + e;
                    float ghr = bsA[e], ghz = bsB[e], ghn = bhn_[e];
                    #pragma unroll
                    for (int p = 0; p < 4; ++p) {
                        ghr += ghp[p][0][eb][jc];
                        ghz += ghp[p][1][eb][jc];
                        ghn += ghp[p][2][eb][jc];
                    }
                    const float rg = fsigmoid(fmaf(x, wih_[e][0], ghr));
                    const float zg = fsigmoid(fmaf(x, wih_[e][1], ghz));
                    const float gin = fmaf(x, wih_[e][2], bin_[e]);
                    const float ng = ftanh(fmaf(rg, ghn, gin));
                    const float hnew = (1.f - zg) * ng + zg * hreg[e];
                    hreg[e] = hnew;
                    const unsigned hb =
                        (unsigned)__builtin_bit_cast(unsigned short, __float2bfloat16(hnew));
                    pack |= hb << (16 * e);
                }
                __hip_atomic_store(
                    (unsigned*)(hnxt + (size_t)(m_base + eb) * HID + j_base + ejc0),
                    pack, __ATOMIC_RELAXED, __HIP_MEMORY_SCOPE_SYSTEM);
                if (t > 0 && jblk == 0 && (tid & 15) == 0)
                    out[(size_t)(m_base + eb) * TSTEPS + (t - 1)] = x;
            }
            __syncthreads();   // drains vmcnt: h stores visible before flag
            if (tid == 0)
                __hip_atomic_store(&bar[mgrp * 32 + jblk], (unsigned)(t + 1),
                                   __ATOMIC_RELAXED, __HIP_MEMORY_SCOPE_SYSTEM);
        } else {
            // ---- t == TSTEPS: final y only ----
            if (ngrp == 0) {
                f32x4 accy0 = {0.f,0.f,0.f,0.f}, accy1 = accy0;
                #pragma unroll
                for (int cc = 0; cc < 8; ++cc) {
                    const int c = (kh << 3) + cc;
                    const int colb = ((c << 6) | (kg << 4)) ^ swz;
                    bf16x8 a0 = *(const bf16x8*)(ldsA + rb0 + colb);
                    bf16x8 a1 = *(const bf16x8*)(ldsA + rb1 + colb);
                    bf16x8 wfv = *(const bf16x8*)(wffn_lds + c * 32 + kg * 8);
                    bf16x8 wb = (l15 == 0) ? wfv : zb;
                    accy0 = MFMA(a0, wb, accy0);
                    accy1 = MFMA(a1, wb, accy1);
                }
                if (l15 == 0) {
                    #pragma unroll
                    for (int r = 0; r < 4; ++r) {
                        ghy[kh][kg * 4 + r]      = accy0[r];
                        ghy[kh][16 + kg * 4 + r] = accy1[r];
                    }
                }
            }
            __syncthreads();
            if (jblk == 0 && tid < 32)
                out[(size_t)(m_base + tid) * TSTEPS + (TSTEPS - 1)] =
                    ghy[0][tid] + ghy[1][tid] + ghy[2][tid] + ghy[3][tid] + bff;
        }
    }
}

extern "C" void kernel_launch(void* const* d_in, const int* in_sizes, int n_in,
                              void* d_out, int out_size, void* d_ws, size_t ws_size,
                              hipStream_t stream)
{
    const float* vectors     = (const float*)d_in[0];
    const float* w_ih        = (const float*)d_in[1];
    const float* w_hh        = (const float*)d_in[2];
    const float* b_ih        = (const float*)d_in[3];
    const float* b_hh        = (const float*)d_in[4];
    const float* w_ffn       = (const float*)d_in[5];
    const float* b_ffn       = (const float*)d_in[6];
    const float* first_input = (const float*)d_in[7];
    float* out = (float*)d_out;

    // workspace carve (~7.4 MB)
    char* p = (char*)d_ws;
    __hip_bfloat16* h_a = (__hip_bfloat16*)p;  p += (size_t)BATCH * HID * 2;
    __hip_bfloat16* h_b = (__hip_bfloat16*)p;  p += (size_t)BATCH * HID * 2;
    __hip_bfloat16* w2  = (__hip_bfloat16*)p;  p += 32LL * 6 * 32 * 64 * 8 * 2;
    unsigned* bar = (unsigned*)p;              p += 1024 * 4;   // flags[256]

    prep_kernel<<<1024, 256, 0, stream>>>(vectors, w_hh, h_a, w2, bar);

    void* args[] = {
        (void*)&vectors, (void*)&w_ih, (void*)&b_ih, (void*)&b_hh,
        (void*)&w_ffn, (void*)&b_ffn, (void*)&first_input,
        (void*)&h_a, (void*)&h_b, (void*)&w2, (void*)&bar, (void*)&out
    };
    hipError_t err = hipLaunchCooperativeKernel((const void*)gru_persistent,
                               dim3(NBLK), dim3(NTHR), args, 0, stream);
    (void)err;
}